// Round 8
// baseline (55.636 us; speedup 1.0000x reference)
//
#include <hip/hip_runtime.h>
#include <math.h>

#define BB 64
#define NN 8192
#define TOTAL_W 9356

typedef _Float16 f16x8 __attribute__((ext_vector_type(8)));
typedef float f32x4 __attribute__((ext_vector_type(4)));
typedef float f32x2 __attribute__((ext_vector_type(2)));
typedef unsigned int u32x2 __attribute__((ext_vector_type(2)));

#define L2E 1.44269504088896340736f
#define LN2 0.6931471805599453f

// ---- LDS layout (bytes) ----
// film2: [4 layers][16 quads][{bias4, wsc4*L2E, bsc4*L2E, wsh4} f32x4] = 4096
#define FILM2_OFF 0
#define A1_OFF    4096                  // A-frags L1: 8192
#define A2_OFF    (A1_OFF + 8192)       // A-frags L2: 8192
#define ACT_OFF   (A2_OFF + 8192)       // Act[128 pts][16 x 8B] swizzled = 16384
#define LDS_BYTES (ACT_OFF + 128 * 128) // 36864 -> 4 blocks/CU

#define MFMA16(a, b, c) __builtin_amdgcn_mfma_f32_16x16x32_f16(a, b, c, 0, 0, 0)
#define EXP2 __builtin_amdgcn_exp2f
#define LOG2 __builtin_amdgcn_logf
#define RCPF __builtin_amdgcn_rcpf

__device__ __forceinline__ f32x2 pfma(f32x2 a, f32x2 b, f32x2 c) {
  return __builtin_elementwise_fma(a, b, c);
}

// One base address per (layer, quad); 4 ds_read_b128 at offsets 0/16/32/48.
__device__ __forceinline__ const f32x4* film_base(const unsigned char* smem, int l, int qd) {
  return (const f32x4*)(smem + FILM2_OFF + ((l * 16 + qd) << 6));
}

// FiLM (+softplus) on a D-quad for one point; acc already includes bias.
template<bool SP>
__device__ __forceinline__ u32x2 film_quad(f32x4 acc, float ctx,
                                           f32x4 wscq, f32x4 bscq, f32x4 wshq) {
  f32x2 ctx2 = {ctx, ctx};
  f32x2 one = {1.f, 1.f};
  f32x2 z0 = pfma(ctx2, (f32x2){wscq.x, wscq.y}, (f32x2){bscq.x, bscq.y});
  f32x2 z1 = pfma(ctx2, (f32x2){wscq.z, wscq.w}, (f32x2){bscq.z, bscq.w});
  f32x2 d0 = {EXP2(-z0.x), EXP2(-z0.y)};  d0 += one;
  f32x2 d1 = {EXP2(-z1.x), EXP2(-z1.y)};  d1 += one;
  f32x2 s0 = {RCPF(d0.x), RCPF(d0.y)};
  f32x2 s1 = {RCPF(d1.x), RCPF(d1.y)};
  f32x2 v0 = pfma(ctx2, (f32x2){wshq.x, wshq.y}, s0 * (f32x2){acc.x, acc.y});
  f32x2 v1 = pfma(ctx2, (f32x2){wshq.z, wshq.w}, s1 * (f32x2){acc.z, acc.w});
  if (SP) {  // softplus = LN2 * log2(1 + 2^(v*L2E))
    f32x2 l2 = {L2E, L2E}, ln = {LN2, LN2};
    f32x2 t0 = v0 * l2, t1 = v1 * l2;
    f32x2 u0 = {EXP2(t0.x), EXP2(t0.y)};  u0 += one;
    f32x2 u1 = {EXP2(t1.x), EXP2(t1.y)};  u1 += one;
    f32x2 g0 = {LOG2(u0.x), LOG2(u0.y)};
    f32x2 g1 = {LOG2(u1.x), LOG2(u1.y)};
    v0 = g0 * ln;
    v1 = g1 * ln;
  }
  auto p01 = __builtin_amdgcn_cvt_pkrtz(v0.x, v0.y);
  auto p23 = __builtin_amdgcn_cvt_pkrtz(v1.x, v1.y);
  u32x2 w;
  w.x = __builtin_bit_cast(unsigned int, p01);
  w.y = __builtin_bit_cast(unsigned int, p23);
  return w;
}

// slot s (4 feats) at 8B-pos ((s>>1)^(pt&7))*2 | (s&1)
__device__ __forceinline__ void act_store(unsigned char* smem, int pt, int slot, u32x2 w) {
  int pos = ((((slot >> 1) ^ (pt & 7)) << 1) | (slot & 1));
  *(u32x2*)(smem + ACT_OFF + pt * 128 + (pos << 3)) = w;
}
__device__ __forceinline__ f16x8 act_load(const unsigned char* smem, int pt, int pair) {
  int gr = pair ^ (pt & 7);
  return *(const f16x8*)(smem + ACT_OFF + pt * 128 + (gr << 4));
}

__global__ __launch_bounds__(256)
void ode_hypernet_kernel(const float* __restrict__ context,
                         const float* __restrict__ y,
                         const float* __restrict__ tnw,
                         float* __restrict__ out) {
  __shared__ __align__(16) unsigned char smem[LDS_BYTES];
  const int b = blockIdx.y;
  const int tid = threadIdx.x;
  const float* __restrict__ wb = tnw + (size_t)b * TOTAL_W;

  const int lane = tid & 63;
  const int wid = tid >> 6;
  const int g = lane >> 4;
  const int col = lane & 15;

  // ---------- staging ----------
  if (tid < 64) {  // film2 params; layer l: bias@bo, wsc@bo+d, bsc@bo+2d, wsh@bo+3d
    const int biaso[4] = {192, 4544, 8896, 9344};
    const int dim[4] = {64, 64, 64, 3};
#pragma unroll
    for (int l = 0; l < 4; ++l) {
      float bv = 0.f, wscv = 0.f, bscv = 0.f, wshv = 0.f;
      if (tid < dim[l]) {
        int bo = biaso[l], d = dim[l];
        bv = wb[bo + tid];
        wscv = wb[bo + d + tid] * L2E;
        bscv = wb[bo + 2 * d + tid] * L2E;
        wshv = wb[bo + 3 * d + tid];
      }
      float* f2 = (float*)(smem + FILM2_OFF + ((l * 16 + (tid >> 2)) << 6)) + (tid & 3);
      f2[0] = bv;      // bias
      f2[4] = wscv;    // wsc*L2E
      f2[8] = bscv;    // bsc*L2E
      f2[12] = wshv;   // wsh
    }
  }
  // A-fragments L1/L2 (A = W^T, 16x32 tiles). Element (f_in, f_out) at
  // aoff + (m*128 + t*64 + h*16 + c)*16 + i*2; m=f_out>>4, c=f_out&15,
  // t=f_in>>5, h=(f_in>>3)&3, i=f_in&7.
#pragma unroll
  for (int L = 0; L < 2; ++L) {
    const int woff = L ? 4800 : 448;
    const int aoff = L ? A2_OFF : A1_OFF;
#pragma unroll
    for (int it = 0; it < 4; ++it) {
      int idx = tid + it * 256;            // 1024 = 64 f_in x 16 quads
      int f_in = idx >> 4;
      int q = idx & 15;
      f32x4 w4 = *(const f32x4*)(wb + woff + f_in * 64 + q * 4);
      int m = q >> 2;
      int c4 = (q & 3) * 4;
      int t = f_in >> 5;
      int h = (f_in >> 3) & 3;
      int i = f_in & 7;
      unsigned char* base = smem + aoff + (m * 128 + t * 64 + h * 16 + c4) * 16 + i * 2;
#pragma unroll
      for (int j = 0; j < 4; ++j)
        *(_Float16*)(base + j * 16) = (_Float16)w4[j];
    }
  }
  // A0 fragments (layer 0, W0 3x64, k=0..2 only) -> registers.
  f16x8 A0r[4];
#pragma unroll
  for (int m = 0; m < 4; ++m) {
#pragma unroll
    for (int i = 0; i < 8; ++i)
      A0r[m][i] = (g == 0 && i < 3) ? (_Float16)wb[i * 64 + 16 * m + col] : (_Float16)0.f;
  }
  // A3 fragments (layer 3, W3 64x3) -> registers.
  f16x8 A3r0, A3r1;
#pragma unroll
  for (int i = 0; i < 8; ++i) {
    A3r0[i] = (col < 3) ? (_Float16)wb[9152 + (8 * g + i) * 3 + col] : (_Float16)0.f;
    A3r1[i] = (col < 3) ? (_Float16)wb[9152 + (32 + 8 * g + i) * 3 + col] : (_Float16)0.f;
  }
  __syncthreads();

  // ---------- per-wave main ----------
  const int pt0 = wid * 32 + col;   // 0..127
  const int pt1 = pt0 + 16;

  // hoist both supersteps' inputs
  const int nb = blockIdx.x * 256;
  const size_t cb = (size_t)b * NN;
  float ctxs[4], yv[4][3];
#pragma unroll
  for (int k = 0; k < 4; ++k) {     // k = ss*2 + (pt1?1:0)
    int n = nb + (k >> 1) * 128 + pt0 + (k & 1) * 16;
    ctxs[k] = context[cb + n];
    const float* yp = y + (cb + n) * 3;
    yv[k][0] = yp[0]; yv[k][1] = yp[1]; yv[k][2] = yp[2];
  }

#pragma unroll
  for (int ss = 0; ss < 2; ++ss) {
    const float ctx0 = ctxs[ss * 2], ctx1 = ctxs[ss * 2 + 1];
    const int n0 = nb + ss * 128 + pt0;
    const int n1 = n0 + 16;

    // B-fragments for layer 0 from y (k=0..2 live in g==0 lanes)
    f16x8 By0 = {0, 0, 0, 0, 0, 0, 0, 0};
    f16x8 By1 = {0, 0, 0, 0, 0, 0, 0, 0};
    if (g == 0) {
      By0[0] = (_Float16)yv[ss * 2][0];
      By0[1] = (_Float16)yv[ss * 2][1];
      By0[2] = (_Float16)yv[ss * 2][2];
      By1[0] = (_Float16)yv[ss * 2 + 1][0];
      By1[1] = (_Float16)yv[ss * 2 + 1][1];
      By1[2] = (_Float16)yv[ss * 2 + 1][2];
    }

    // ----- layer 0 (3 -> 64) on MFMA (single k-tile) -----
#pragma unroll
    for (int m = 0; m < 4; ++m) {
      const f32x4* fb = film_base(smem, 0, 4 * m + g);
      f32x4 biasq = fb[0], wscq = fb[1], bscq = fb[2], wshq = fb[3];
      f32x4 c0 = biasq, c1 = biasq;
      c0 = MFMA16(A0r[m], By0, c0);
      c1 = MFMA16(A0r[m], By1, c1);
      act_store(smem, pt0, 4 * m + g, film_quad<true>(c0, ctx0, wscq, bscq, wshq));
      act_store(smem, pt1, 4 * m + g, film_quad<true>(c1, ctx1, wscq, bscq, wshq));
    }

    // ----- layers 1,2 (64 -> 64) on MFMA -----
#pragma unroll
    for (int L = 1; L <= 2; ++L) {
      const int aoff = (L == 1) ? A1_OFF : A2_OFF;
      f16x8 B00 = act_load(smem, pt0, g);
      f16x8 B01 = act_load(smem, pt0, 4 + g);
      f16x8 B10 = act_load(smem, pt1, g);
      f16x8 B11 = act_load(smem, pt1, 4 + g);
#pragma unroll
      for (int m = 0; m < 4; ++m) {
        const f32x4* fb = film_base(smem, L, 4 * m + g);
        f32x4 biasq = fb[0], wscq = fb[1], bscq = fb[2], wshq = fb[3];
        f16x8 a0 = *(const f16x8*)(smem + aoff + ((m * 2 + 0) * 64 + lane) * 16);
        f16x8 a1 = *(const f16x8*)(smem + aoff + ((m * 2 + 1) * 64 + lane) * 16);
        f32x4 c0 = biasq, c1 = biasq;
        c0 = MFMA16(a0, B00, c0);
        c0 = MFMA16(a1, B01, c0);
        c1 = MFMA16(a0, B10, c1);
        c1 = MFMA16(a1, B11, c1);
        act_store(smem, pt0, 4 * m + g, film_quad<true>(c0, ctx0, wscq, bscq, wshq));
        act_store(smem, pt1, 4 * m + g, film_quad<true>(c1, ctx1, wscq, bscq, wshq));
      }
    }

    // ----- layer 3 (64 -> 3) on MFMA (A from regs), FiLM only -----
    {
      f16x8 B00 = act_load(smem, pt0, g);
      f16x8 B01 = act_load(smem, pt0, 4 + g);
      f16x8 B10 = act_load(smem, pt1, g);
      f16x8 B11 = act_load(smem, pt1, 4 + g);
      const f32x4* fb = film_base(smem, 3, g);
      f32x4 biasq = fb[0], wscq = fb[1], bscq = fb[2], wshq = fb[3];
      f32x4 c0 = biasq, c1 = biasq;
      c0 = MFMA16(A3r0, B00, c0);
      c0 = MFMA16(A3r1, B01, c0);
      c1 = MFMA16(A3r0, B10, c1);
      c1 = MFMA16(A3r1, B11, c1);
      if (g == 0) {
#pragma unroll
        for (int p = 0; p < 2; ++p) {
          f32x4 c = p ? c1 : c0;
          float ctx = p ? ctx1 : ctx0;
          int n = p ? n1 : n0;
#pragma unroll
          for (int j = 0; j < 3; ++j) {
            float z = fmaf(ctx, wscq[j], bscq[j]);
            float s = RCPF(1.0f + EXP2(-z));
            float v = fmaf(ctx, wshq[j], s * c[j]);
            out[((size_t)b * NN + n) * 3 + j] = v;
          }
        }
      }
    }
  }
}

extern "C" void kernel_launch(void* const* d_in, const int* in_sizes, int n_in,
                              void* d_out, int out_size, void* d_ws, size_t ws_size,
                              hipStream_t stream) {
  const float* context = (const float*)d_in[0];  // (64, 8192)
  const float* y       = (const float*)d_in[1];  // (64, 8192, 3)
  const float* tnw     = (const float*)d_in[2];  // (64, 9356)
  float* out           = (float*)d_out;          // (64, 8192, 3)

  dim3 grid(NN / 256, BB, 1);  // 2048 blocks, 256 points each (2 ss x 128)
  dim3 block(256, 1, 1);
  ode_hypernet_kernel<<<grid, block, 0, stream>>>(context, y, tnw, out);
}

// Round 9
// 55.456 us; speedup vs baseline: 1.0033x; 1.0033x over previous
//
#include <hip/hip_runtime.h>
#include <math.h>

#define BB 64
#define NN 8192
#define TOTAL_W 9356

typedef _Float16 f16x8 __attribute__((ext_vector_type(8)));
typedef float f32x4 __attribute__((ext_vector_type(4)));
typedef float f32x2 __attribute__((ext_vector_type(2)));
typedef unsigned int u32x2 __attribute__((ext_vector_type(2)));

#define L2E 1.44269504088896340736f
#define LN2 0.6931471805599453f

// ---- ws layout (bytes, per b) ----
#define WS_FILM 0        // film2: [4 l][16 quad][{bias4,wsc4*L2E,bsc4*L2E,wsh4}] = 4096
#define WS_A1   4096     // A-frags L1 = 8192
#define WS_A2   12288    // A-frags L2 = 8192
#define WS_A0   20480    // A0 frag image [4 m][64 lane] f16x8 = 4096
#define WS_A3   24576    // A3 frag image [2 t][64 lane] f16x8 = 2048
#define WSB     26624

// ---- LDS layout (bytes) ---- (first 20480 B == ws[0..20480) verbatim)
#define FILM2_OFF 0
#define A1_OFF    4096
#define A2_OFF    12288
#define ACT_OFF   20480                 // Act[128 pts][16 x 8B] swizzled = 16384
#define LDS_BYTES (ACT_OFF + 128 * 128) // 36864 -> 4 blocks/CU

#define MFMA16(a, b, c) __builtin_amdgcn_mfma_f32_16x16x32_f16(a, b, c, 0, 0, 0)
#define EXP2 __builtin_amdgcn_exp2f
#define LOG2 __builtin_amdgcn_logf
#define RCPF __builtin_amdgcn_rcpf

__device__ __forceinline__ f32x2 pfma(f32x2 a, f32x2 b, f32x2 c) {
  return __builtin_elementwise_fma(a, b, c);
}

__device__ __forceinline__ const f32x4* film_base(const unsigned char* smem, int l, int qd) {
  return (const f32x4*)(smem + FILM2_OFF + ((l * 16 + qd) << 6));
}

// FiLM (+softplus) on a D-quad for one point; acc already includes bias.
template<bool SP>
__device__ __forceinline__ u32x2 film_quad(f32x4 acc, float ctx,
                                           f32x4 wscq, f32x4 bscq, f32x4 wshq) {
  f32x2 ctx2 = {ctx, ctx};
  f32x2 one = {1.f, 1.f};
  f32x2 z0 = pfma(ctx2, (f32x2){wscq.x, wscq.y}, (f32x2){bscq.x, bscq.y});
  f32x2 z1 = pfma(ctx2, (f32x2){wscq.z, wscq.w}, (f32x2){bscq.z, bscq.w});
  f32x2 d0 = {EXP2(-z0.x), EXP2(-z0.y)};  d0 += one;
  f32x2 d1 = {EXP2(-z1.x), EXP2(-z1.y)};  d1 += one;
  f32x2 s0 = {RCPF(d0.x), RCPF(d0.y)};
  f32x2 s1 = {RCPF(d1.x), RCPF(d1.y)};
  f32x2 v0 = pfma(ctx2, (f32x2){wshq.x, wshq.y}, s0 * (f32x2){acc.x, acc.y});
  f32x2 v1 = pfma(ctx2, (f32x2){wshq.z, wshq.w}, s1 * (f32x2){acc.z, acc.w});
  if (SP) {  // softplus = LN2 * log2(1 + 2^(v*L2E))
    f32x2 l2 = {L2E, L2E}, ln = {LN2, LN2};
    f32x2 t0 = v0 * l2, t1 = v1 * l2;
    f32x2 u0 = {EXP2(t0.x), EXP2(t0.y)};  u0 += one;
    f32x2 u1 = {EXP2(t1.x), EXP2(t1.y)};  u1 += one;
    f32x2 g0 = {LOG2(u0.x), LOG2(u0.y)};
    f32x2 g1 = {LOG2(u1.x), LOG2(u1.y)};
    v0 = g0 * ln;
    v1 = g1 * ln;
  }
  auto p01 = __builtin_amdgcn_cvt_pkrtz(v0.x, v0.y);
  auto p23 = __builtin_amdgcn_cvt_pkrtz(v1.x, v1.y);
  u32x2 w;
  w.x = __builtin_bit_cast(unsigned int, p01);
  w.y = __builtin_bit_cast(unsigned int, p23);
  return w;
}

// slot s (4 feats) at 8B-pos ((s>>1)^(pt&7))*2 | (s&1)
__device__ __forceinline__ void act_store(unsigned char* smem, int pt, int slot, u32x2 w) {
  int pos = ((((slot >> 1) ^ (pt & 7)) << 1) | (slot & 1));
  *(u32x2*)(smem + ACT_OFF + pt * 128 + (pos << 3)) = w;
}
__device__ __forceinline__ f16x8 act_load(const unsigned char* smem, int pt, int pair) {
  int gr = pair ^ (pt & 7);
  return *(const f16x8*)(smem + ACT_OFF + pt * 128 + (gr << 4));
}

// ============ prep kernel: one block per b, builds ws images ============
__global__ __launch_bounds__(512)
void ode_prep_kernel(const float* __restrict__ tnw, unsigned char* __restrict__ ws) {
  const int b = blockIdx.x;
  const int tid = threadIdx.x;
  const float* __restrict__ wb = tnw + (size_t)b * TOTAL_W;
  unsigned char* __restrict__ wsb = ws + (size_t)b * WSB;

  // film2 params; layer l: bias@bo, wsc@bo+d, bsc@bo+2d, wsh@bo+3d
  if (tid < 64) {
    const int biaso[4] = {192, 4544, 8896, 9344};
    const int dim[4] = {64, 64, 64, 3};
#pragma unroll
    for (int l = 0; l < 4; ++l) {
      float bv = 0.f, wscv = 0.f, bscv = 0.f, wshv = 0.f;
      if (tid < dim[l]) {
        int bo = biaso[l], d = dim[l];
        bv = wb[bo + tid];
        wscv = wb[bo + d + tid] * L2E;
        bscv = wb[bo + 2 * d + tid] * L2E;
        wshv = wb[bo + 3 * d + tid];
      }
      float* f2 = (float*)(wsb + WS_FILM + ((l * 16 + (tid >> 2)) << 6)) + (tid & 3);
      f2[0] = bv;
      f2[4] = wscv;
      f2[8] = bscv;
      f2[12] = wshv;
    }
  }
  // A-fragments L1/L2 (A = W^T): row r = m*128 + t*64 + lane.
  // lane holds A[row=lane&15][k=8*(lane>>4)+i]: f_out=16m+(lane&15), f_in=32t+8*(lane>>4)+i
#pragma unroll
  for (int L = 0; L < 2; ++L) {
    const int woff = L ? 4800 : 448;
    unsigned char* dst = wsb + (L ? WS_A2 : WS_A1);
    int r = tid;  // 512 threads, 512 rows
    int lane_r = r & 63;
    int t = (r >> 6) & 1;
    int m = r >> 7;
    int f_out = 16 * m + (lane_r & 15);
    int f_in0 = 32 * t + 8 * (lane_r >> 4);
    f16x8 h;
#pragma unroll
    for (int i = 0; i < 8; ++i) h[i] = (_Float16)wb[woff + (f_in0 + i) * 64 + f_out];
    *(f16x8*)(dst + r * 16) = h;
  }
  // A0 register image: [m][lane], lane=(g,col); k=0..2 live in g==0
  if (tid < 256) {
    int m = tid >> 6;
    int lane = tid & 63;
    int g = lane >> 4, col = lane & 15;
    f16x8 h = {0, 0, 0, 0, 0, 0, 0, 0};
    if (g == 0) {
#pragma unroll
      for (int i = 0; i < 3; ++i) h[i] = (_Float16)wb[i * 64 + 16 * m + col];
    }
    *(f16x8*)(wsb + WS_A0 + tid * 16) = h;
  }
  // A3 register image: [t][lane]
  if (tid < 128) {
    int t = tid >> 6;
    int lane = tid & 63;
    int g = lane >> 4, col = lane & 15;
    f16x8 h = {0, 0, 0, 0, 0, 0, 0, 0};
    if (col < 3) {
#pragma unroll
      for (int i = 0; i < 8; ++i)
        h[i] = (_Float16)wb[9152 + (32 * t + 8 * g + i) * 3 + col];
    }
    *(f16x8*)(wsb + WS_A3 + tid * 16) = h;
  }
}

// ============ main kernel ============
__global__ __launch_bounds__(256)
void ode_hypernet_kernel(const float* __restrict__ context,
                         const float* __restrict__ y,
                         const unsigned char* __restrict__ ws,
                         float* __restrict__ out) {
  __shared__ __align__(16) unsigned char smem[LDS_BYTES];
  const int b = blockIdx.y;
  const int tid = threadIdx.x;
  const unsigned char* __restrict__ wsb = ws + (size_t)b * WSB;

  const int lane = tid & 63;
  const int wid = tid >> 6;
  const int g = lane >> 4;
  const int col = lane & 15;

  // ---------- staging: linear coalesced copy of film2+A1+A2 ----------
#pragma unroll
  for (int it = 0; it < 5; ++it) {
    int i = tid + it * 256;  // i < 1280 (20480 B)
    *(f32x4*)(smem + i * 16) = *(const f32x4*)(wsb + i * 16);
  }
  // register fragments straight from ws (16B coalesced loads)
  f16x8 A0r[4];
#pragma unroll
  for (int m = 0; m < 4; ++m)
    A0r[m] = *(const f16x8*)(wsb + WS_A0 + (m * 64 + lane) * 16);
  f16x8 A3r0 = *(const f16x8*)(wsb + WS_A3 + lane * 16);
  f16x8 A3r1 = *(const f16x8*)(wsb + WS_A3 + (64 + lane) * 16);
  __syncthreads();

  // ---------- per-wave main ----------
  const int pt0 = wid * 32 + col;  // 0..127
  const int pt1 = pt0 + 16;

  // hoist both supersteps' inputs
  const int nb = blockIdx.x * 256;
  const size_t cb = (size_t)b * NN;
  float ctxs[4], yv[4][3];
#pragma unroll
  for (int k = 0; k < 4; ++k) {  // k = ss*2 + (pt1?1:0)
    int n = nb + (k >> 1) * 128 + pt0 + (k & 1) * 16;
    ctxs[k] = context[cb + n];
    const float* yp = y + (cb + n) * 3;
    yv[k][0] = yp[0]; yv[k][1] = yp[1]; yv[k][2] = yp[2];
  }

#pragma unroll
  for (int ss = 0; ss < 2; ++ss) {
    const float ctx0 = ctxs[ss * 2], ctx1 = ctxs[ss * 2 + 1];
    const int n0 = nb + ss * 128 + pt0;
    const int n1 = n0 + 16;

    // B-fragments for layer 0 from y (k=0..2 live in g==0 lanes)
    f16x8 By0 = {0, 0, 0, 0, 0, 0, 0, 0};
    f16x8 By1 = {0, 0, 0, 0, 0, 0, 0, 0};
    if (g == 0) {
      By0[0] = (_Float16)yv[ss * 2][0];
      By0[1] = (_Float16)yv[ss * 2][1];
      By0[2] = (_Float16)yv[ss * 2][2];
      By1[0] = (_Float16)yv[ss * 2 + 1][0];
      By1[1] = (_Float16)yv[ss * 2 + 1][1];
      By1[2] = (_Float16)yv[ss * 2 + 1][2];
    }

    // ----- layer 0 (3 -> 64) on MFMA (single k-tile) -----
#pragma unroll
    for (int m = 0; m < 4; ++m) {
      const f32x4* fb = film_base(smem, 0, 4 * m + g);
      f32x4 biasq = fb[0], wscq = fb[1], bscq = fb[2], wshq = fb[3];
      f32x4 c0 = biasq, c1 = biasq;
      c0 = MFMA16(A0r[m], By0, c0);
      c1 = MFMA16(A0r[m], By1, c1);
      act_store(smem, pt0, 4 * m + g, film_quad<true>(c0, ctx0, wscq, bscq, wshq));
      act_store(smem, pt1, 4 * m + g, film_quad<true>(c1, ctx1, wscq, bscq, wshq));
    }

    // ----- layers 1,2 (64 -> 64) on MFMA -----
#pragma unroll
    for (int L = 1; L <= 2; ++L) {
      const int aoff = (L == 1) ? A1_OFF : A2_OFF;
      f16x8 B00 = act_load(smem, pt0, g);
      f16x8 B01 = act_load(smem, pt0, 4 + g);
      f16x8 B10 = act_load(smem, pt1, g);
      f16x8 B11 = act_load(smem, pt1, 4 + g);
#pragma unroll
      for (int m = 0; m < 4; ++m) {
        const f32x4* fb = film_base(smem, L, 4 * m + g);
        f32x4 biasq = fb[0], wscq = fb[1], bscq = fb[2], wshq = fb[3];
        f16x8 a0 = *(const f16x8*)(smem + aoff + ((m * 2 + 0) * 64 + lane) * 16);
        f16x8 a1 = *(const f16x8*)(smem + aoff + ((m * 2 + 1) * 64 + lane) * 16);
        f32x4 c0 = biasq, c1 = biasq;
        c0 = MFMA16(a0, B00, c0);
        c0 = MFMA16(a1, B01, c0);
        c1 = MFMA16(a0, B10, c1);
        c1 = MFMA16(a1, B11, c1);
        act_store(smem, pt0, 4 * m + g, film_quad<true>(c0, ctx0, wscq, bscq, wshq));
        act_store(smem, pt1, 4 * m + g, film_quad<true>(c1, ctx1, wscq, bscq, wshq));
      }
    }

    // ----- layer 3 (64 -> 3) on MFMA (A from regs), FiLM only -----
    {
      f16x8 B00 = act_load(smem, pt0, g);
      f16x8 B01 = act_load(smem, pt0, 4 + g);
      f16x8 B10 = act_load(smem, pt1, g);
      f16x8 B11 = act_load(smem, pt1, 4 + g);
      const f32x4* fb = film_base(smem, 3, g);
      f32x4 biasq = fb[0], wscq = fb[1], bscq = fb[2], wshq = fb[3];
      f32x4 c0 = biasq, c1 = biasq;
      c0 = MFMA16(A3r0, B00, c0);
      c0 = MFMA16(A3r1, B01, c0);
      c1 = MFMA16(A3r0, B10, c1);
      c1 = MFMA16(A3r1, B11, c1);
      if (g == 0) {
#pragma unroll
        for (int p = 0; p < 2; ++p) {
          f32x4 c = p ? c1 : c0;
          float ctx = p ? ctx1 : ctx0;
          int n = p ? n1 : n0;
#pragma unroll
          for (int j = 0; j < 3; ++j) {
            float z = fmaf(ctx, wscq[j], bscq[j]);
            float s = RCPF(1.0f + EXP2(-z));
            float v = fmaf(ctx, wshq[j], s * c[j]);
            out[((size_t)b * NN + n) * 3 + j] = v;
          }
        }
      }
    }
  }
}

extern "C" void kernel_launch(void* const* d_in, const int* in_sizes, int n_in,
                              void* d_out, int out_size, void* d_ws, size_t ws_size,
                              hipStream_t stream) {
  const float* context = (const float*)d_in[0];  // (64, 8192)
  const float* y       = (const float*)d_in[1];  // (64, 8192, 3)
  const float* tnw     = (const float*)d_in[2];  // (64, 9356)
  float* out           = (float*)d_out;          // (64, 8192, 3)
  unsigned char* ws    = (unsigned char*)d_ws;   // needs 64*26624 = 1,703,936 B

  ode_prep_kernel<<<dim3(BB, 1, 1), dim3(512, 1, 1), 0, stream>>>(tnw, ws);
  dim3 grid(NN / 256, BB, 1);  // 2048 blocks, 256 points each (2 ss x 128)
  dim3 block(256, 1, 1);
  ode_hypernet_kernel<<<grid, block, 0, stream>>>(context, y, ws, out);
}